// Round 1
// baseline (1097.194 us; speedup 1.0000x reference)
//
#include <hip/hip_runtime.h>
#include <stdint.h>

#define Bn 128
#define Ln 1024
#define H2n 1024
#define Tn 9

// ---------------------------------------------------------------------------
// Workspace layout (ws re-poisoned 0xAA before every launch; we write before read)
//   emissions : float  [B*L*T]   offset 0                     (4,718,592 B)
//   hist      : uint8  [B*L*T]   offset 4718592               (1,179,648 B)
//   last_tag  : int    [B]       offset 5898240               (512 B)
//   length    : int    [B]       offset 5898752               (512 B)
// ---------------------------------------------------------------------------

// mask storage mode detection: lengths>=512 so mask[0][1..4] are all true(=1).
//   u8 storage : byte[1]==1
//   i32 storage: byte[1]==0, byte[4]==1
//   i64 storage: byte[1]==0, byte[4]==0
__device__ __forceinline__ int mask_mode(const void* m) {
    const uint8_t* p = (const uint8_t*)m;
    return (p[1] == 1) ? 0 : ((p[4] == 1) ? 1 : 2);
}
__device__ __forceinline__ bool mask_get(const void* m, int mode, int idx) {
    if (mode == 0) return ((const uint8_t*)m)[idx] != 0;
    if (mode == 1) return ((const int*)m)[idx] != 0;
    return ((const long long*)m)[idx] != 0;
}

// ---------------------------------------------------------------------------
// K1: emissions[b,l,t] = dot(enc[b,l,:], W[t,:]) + bias[t]
// wave-per-row, W staged in LDS, float4 global loads, butterfly reduction.
// grid = 1024 blocks x 256 thr -> 4096 waves x 32 rows each = 131072 rows
// ---------------------------------------------------------------------------
__global__ __launch_bounds__(256) void k_emis(const float* __restrict__ enc,
                                              const float* __restrict__ W,
                                              const float* __restrict__ bias,
                                              float* __restrict__ emis) {
    __shared__ float Wl[Tn * H2n];
    __shared__ float bl[Tn];
    const int tid = threadIdx.x;
    for (int i = tid; i < Tn * H2n; i += 256) Wl[i] = W[i];
    if (tid < Tn) bl[tid] = bias[tid];
    __syncthreads();

    const int lane = tid & 63;
    const int wave = tid >> 6;
    const int wid  = blockIdx.x * 4 + wave;      // 0..4095
    const int row0 = wid * 32;

    for (int rr = 0; rr < 32; ++rr) {
        const int row = row0 + rr;
        const float4* rp = (const float4*)(enc + (size_t)row * H2n);
        float acc[Tn];
#pragma unroll
        for (int t = 0; t < Tn; ++t) acc[t] = 0.f;
#pragma unroll
        for (int j = 0; j < 4; ++j) {
            const float4 ev = rp[lane + j * 64];
#pragma unroll
            for (int t = 0; t < Tn; ++t) {
                const float4 wv = ((const float4*)(Wl + t * H2n))[lane + j * 64];
                acc[t] += ev.x * wv.x + ev.y * wv.y + ev.z * wv.z + ev.w * wv.w;
            }
        }
#pragma unroll
        for (int t = 0; t < Tn; ++t) {
#pragma unroll
            for (int off = 32; off > 0; off >>= 1)
                acc[t] += __shfl_xor(acc[t], off, 64);
        }
        if (lane == 0) {
            float* op = emis + (size_t)row * Tn;
#pragma unroll
            for (int t = 0; t < Tn; ++t) op[t] = acc[t] + bl[t];
        }
    }
}

// ---------------------------------------------------------------------------
// K2: Viterbi forward. One wave per batch. Lane j (j<9) owns tag column j.
// Score vector replicated in every lane via shuffles. History as u8.
// ---------------------------------------------------------------------------
__global__ __launch_bounds__(64) void k_viterbi(const float* __restrict__ emis,
                                                const void* __restrict__ maskraw,
                                                const float* __restrict__ startT,
                                                const float* __restrict__ endT,
                                                const float* __restrict__ trans,
                                                uint8_t* __restrict__ hist,
                                                float* __restrict__ score_out,
                                                int* __restrict__ last_tag,
                                                int* __restrict__ length_out) {
    const int b = blockIdx.x;
    const int lane = threadIdx.x;
    const int j = (lane < Tn) ? lane : 0;   // clamp: lanes >=9 shadow lane 0
    const int mode = mask_mode(maskraw);

    // per-batch length: mask row is a prefix of trues; popcount it in parallel.
    int cnt = 0;
    for (int k = 0; k < Ln / 64; ++k)
        cnt += mask_get(maskraw, mode, b * Ln + lane + k * 64) ? 1 : 0;
#pragma unroll
    for (int off = 32; off > 0; off >>= 1) cnt += __shfl_xor(cnt, off, 64);
    const int len = cnt;   // all lanes agree

    // transitions column j (tc[i] = trans[i][j]) in registers
    float tc[Tn];
#pragma unroll
    for (int i = 0; i < Tn; ++i) tc[i] = trans[i * Tn + j];

    const float* eb = emis + (size_t)b * Ln * Tn;
    uint8_t* hb = hist + (size_t)b * Ln * Tn;

    float s[Tn];       // full score vector, replicated in every lane
    float myscore;     // this lane's own score (avoids dynamic reg indexing)
    {
        const float s0 = startT[j] + eb[j];
        myscore = s0;
#pragma unroll
        for (int i = 0; i < Tn; ++i) s[i] = __shfl(s0, i, 64);
    }

    float emit_next = eb[Tn + j];   // prefetch l=1
    for (int l = 1; l < Ln; ++l) {
        const float emit = emit_next;
        if (l + 1 < Ln) emit_next = eb[(l + 1) * Tn + j];
        const bool m = (l < len);

        float bi = s[0] + tc[0];
        int idx = 0;
#pragma unroll
        for (int i = 1; i < Tn; ++i) {
            const float c = s[i] + tc[i];
            if (c > bi) { bi = c; idx = i; }   // strict > keeps first max
        }
        const float nv = m ? (bi + emit) : myscore;
        const int   ni = m ? idx : j;
        myscore = nv;
        if (lane < Tn) hb[l * Tn + lane] = (uint8_t)ni;
#pragma unroll
        for (int i = 0; i < Tn; ++i) s[i] = __shfl(nv, i, 64);
    }

    // finalize: every lane computes best/argmax identically (endT is tiny)
    float fb = s[0] + endT[0];
    int fi = 0;
#pragma unroll
    for (int i = 1; i < Tn; ++i) {
        const float c = s[i] + endT[i];
        if (c > fb) { fb = c; fi = i; }
    }
    if (lane == 0) {
        score_out[b] = fb;
        last_tag[b] = fi;
        length_out[b] = len;
    }
}

// ---------------------------------------------------------------------------
// K3: backtrace, one thread per batch. hist row (9 KB) is L1/L2-resident.
// ---------------------------------------------------------------------------
__global__ __launch_bounds__(64) void k_backtrace(const uint8_t* __restrict__ hist,
                                                  const int* __restrict__ last_tag,
                                                  const int* __restrict__ length,
                                                  float* __restrict__ tags) {
    const int b = blockIdx.x * 64 + threadIdx.x;
    if (b >= Bn) return;
    const uint8_t* hb = hist + (size_t)b * Ln * Tn;
    const int len = length[b];
    int tag = last_tag[b];
    for (int l = Ln - 1; l >= 1; --l) {
        tags[b * Ln + l] = (l < len) ? (float)tag : 0.f;
        tag = hb[l * Tn + tag];
    }
    tags[b * Ln + 0] = (float)tag;   // mask[:,0] always true
}

// ---------------------------------------------------------------------------
extern "C" void kernel_launch(void* const* d_in, const int* in_sizes, int n_in,
                              void* d_out, int out_size, void* d_ws, size_t ws_size,
                              hipStream_t stream) {
    const float* enc    = (const float*)d_in[0];
    const void*  mask   = d_in[1];
    const float* W      = (const float*)d_in[2];
    const float* bias   = (const float*)d_in[3];
    const float* startT = (const float*)d_in[4];
    const float* endT   = (const float*)d_in[5];
    const float* trans  = (const float*)d_in[6];

    float* out_tags  = (float*)d_out;
    float* out_score = out_tags + (size_t)Bn * Ln;

    char* ws = (char*)d_ws;
    float*   emis     = (float*)ws;
    uint8_t* hist     = (uint8_t*)(ws + (size_t)Bn * Ln * Tn * 4);
    int*     last_tag = (int*)(ws + (size_t)Bn * Ln * Tn * 5);
    int*     length   = last_tag + Bn;

    k_emis<<<1024, 256, 0, stream>>>(enc, W, bias, emis);
    k_viterbi<<<Bn, 64, 0, stream>>>(emis, mask, startT, endT, trans,
                                     hist, out_score, last_tag, length);
    k_backtrace<<<(Bn + 63) / 64, 64, 0, stream>>>(hist, last_tag, length, out_tags);
}

// Round 2
// 770.206 us; speedup vs baseline: 1.4245x; 1.4245x over previous
//
#include <hip/hip_runtime.h>
#include <stdint.h>

#define Bn 128
#define Ln 1024
#define H2n 1024
#define Tn 9
#define Cn 32          // chunks per batch (steps l=1..1023 split into 32-step chunks)
#define Sn 32          // steps per chunk (last chunk has 31)
#define GPW 7          // chunk-groups per wave (7*9 = 63 active lanes)
#define WPB 5          // waves per batch = ceil(Cn/GPW)
#define EP 12          // padded emissions row stride (floats)
#define HP 16          // hist/comp row stride (bytes)
#define NEG (-1e30f)

// ---------------------------------------------------------------------------
// ws layout (bytes):
//   emis_p : f32 [B][L][EP]        @ 0          (6,291,456)
//   Mws    : f32 [B][Cn][9][EP]    @ 6291456    (1,769,472)
//   sb     : f32 [B][Cn][EP]       @ 8060928    (196,608)
//   hist   : u8  [B][L][HP]        @ 8257536    (2,097,152)
//   comp   : u8  [B][Cn][HP]       @ 10354688   (65,536)
//   lenw   : i32 [B]               @ 10420224
//   ltag   : i32 [B]               @ 10420736
//   bt     : u8  [B][Cn]           @ 10421248
// ---------------------------------------------------------------------------

// mask storage detection (lengths>=512 so mask[0][1..4] all true):
__device__ __forceinline__ int mask_mode(const void* m) {
    const uint8_t* p = (const uint8_t*)m;
    return (p[1] == 1) ? 0 : ((p[4] == 1) ? 1 : 2);
}
__device__ __forceinline__ bool mask_get(const void* m, int mode, int idx) {
    if (mode == 0) return ((const uint8_t*)m)[idx] != 0;
    if (mode == 1) return ((const int*)m)[idx] != 0;
    return ((const long long*)m)[idx] != 0;
}

// K0: per-batch length (mask row is a prefix of trues)
__global__ __launch_bounds__(64) void k_len(const void* __restrict__ mask,
                                            int* __restrict__ lenw) {
    const int b = blockIdx.x;
    const int lane = threadIdx.x;
    const int mode = mask_mode(mask);
    int cnt = 0;
    for (int k = 0; k < Ln / 64; ++k)
        cnt += mask_get(mask, mode, b * Ln + lane + k * 64) ? 1 : 0;
#pragma unroll
    for (int off = 32; off > 0; off >>= 1) cnt += __shfl_xor(cnt, off, 64);
    if (lane == 0) lenw[b] = cnt;
}

// K1: emissions, padded to EP floats/row. wave-per-row, W in LDS.
__global__ __launch_bounds__(256) void k_emis(const float* __restrict__ enc,
                                              const float* __restrict__ W,
                                              const float* __restrict__ bias,
                                              float* __restrict__ emis) {
    __shared__ float Wl[Tn * H2n];
    __shared__ float bl[Tn];
    const int tid = threadIdx.x;
    for (int i = tid; i < Tn * H2n; i += 256) Wl[i] = W[i];
    if (tid < Tn) bl[tid] = bias[tid];
    __syncthreads();

    const int lane = tid & 63;
    const int wave = tid >> 6;
    const int wid  = blockIdx.x * 4 + wave;
    const int row0 = wid * 32;

    for (int rr = 0; rr < 32; ++rr) {
        const int row = row0 + rr;
        const float4* rp = (const float4*)(enc + (size_t)row * H2n);
        float acc[Tn];
#pragma unroll
        for (int t = 0; t < Tn; ++t) acc[t] = 0.f;
#pragma unroll
        for (int j = 0; j < 4; ++j) {
            const float4 ev = rp[lane + j * 64];
#pragma unroll
            for (int t = 0; t < Tn; ++t) {
                const float4 wv = ((const float4*)(Wl + t * H2n))[lane + j * 64];
                acc[t] += ev.x * wv.x + ev.y * wv.y + ev.z * wv.z + ev.w * wv.w;
            }
        }
#pragma unroll
        for (int t = 0; t < Tn; ++t) {
#pragma unroll
            for (int off = 32; off > 0; off >>= 1)
                acc[t] += __shfl_xor(acc[t], off, 64);
        }
        if (lane == 0) {
            float* op = emis + (size_t)row * EP;
            *((float4*)op)       = make_float4(acc[0] + bl[0], acc[1] + bl[1],
                                               acc[2] + bl[2], acc[3] + bl[3]);
            *((float4*)(op + 4)) = make_float4(acc[4] + bl[4], acc[5] + bl[5],
                                               acc[6] + bl[6], acc[7] + bl[7]);
            *((float4*)(op + 8)) = make_float4(acc[8] + bl[8], 0.f, 0.f, 0.f);
        }
    }
}

// K2: per-chunk max-plus matrix product. lane = c_sub*9 + i holds row i.
__global__ __launch_bounds__(64) void k_chunkmat(const float* __restrict__ emis,
                                                 const float* __restrict__ trans,
                                                 const int* __restrict__ lenw,
                                                 float* __restrict__ Mws) {
    const int b = blockIdx.x / WPB;
    const int w = blockIdx.x % WPB;
    const int lane = threadIdx.x;
    const int cs = lane / 9, i = lane % 9;
    const int c = w * GPW + cs;
    const bool act = (lane < 63) && (c < Cn);
    const int cc = act ? c : 0;
    const int len = lenw[b];

    float tr[81];
#pragma unroll
    for (int k = 0; k < 81; ++k) tr[k] = trans[k];

    float m[9];
#pragma unroll
    for (int k = 0; k < 9; ++k) m[k] = (k == i) ? 0.f : NEG;

    const float* erow = emis + (size_t)b * Ln * EP;
    const int l0 = 1 + cc * Sn;
#pragma unroll
    for (int t = 0; t < Sn; ++t) {
        const int l = l0 + t;
        const int le = (l < Ln) ? l : (Ln - 1);
        const float4 ea = *((const float4*)(erow + le * EP));
        const float4 eb4 = *((const float4*)(erow + le * EP + 4));
        const float e8v = erow[le * EP + 8];
        const float e[9] = {ea.x, ea.y, ea.z, ea.w, eb4.x, eb4.y, eb4.z, eb4.w, e8v};
        const bool ds = act && (l < len);   // l<len implies l<Ln
        float nm[9];
#pragma unroll
        for (int j = 0; j < 9; ++j) {
            float v = m[0] + tr[j];
#pragma unroll
            for (int k = 1; k < 9; ++k) v = fmaxf(v, m[k] + tr[k * 9 + j]);
            nm[j] = v + e[j];
        }
#pragma unroll
        for (int j = 0; j < 9; ++j) m[j] = ds ? nm[j] : m[j];
    }
    if (act) {
        float* Mr = Mws + ((size_t)(b * Cn + c) * 9 + i) * EP;
        *((float4*)Mr)       = make_float4(m[0], m[1], m[2], m[3]);
        *((float4*)(Mr + 4)) = make_float4(m[4], m[5], m[6], m[7]);
        *((float4*)(Mr + 8)) = make_float4(m[8], 0.f, 0.f, 0.f);
    }
}

// K3: per-batch sequential stitch over chunk matrices -> boundary vectors,
// final best_score and last_tag.
__global__ __launch_bounds__(64) void k_stitch_scores(const float* __restrict__ emis,
                                                      const float* __restrict__ Mws,
                                                      const float* __restrict__ startT,
                                                      const float* __restrict__ endT,
                                                      float* __restrict__ sb,
                                                      float* __restrict__ score_out,
                                                      int* __restrict__ ltag) {
    const int b = blockIdx.x;
    const int lane = threadIdx.x;
    const int j = (lane < Tn) ? lane : 0;
    float s = startT[j] + emis[(size_t)b * Ln * EP + j];
    for (int c = 0; c < Cn; ++c) {
        if (lane < Tn) sb[(size_t)(b * Cn + c) * EP + j] = s;
        float sf[9];
#pragma unroll
        for (int k = 0; k < 9; ++k) sf[k] = __shfl(s, k, 64);
        const float* Mc = Mws + (size_t)(b * Cn + c) * 9 * EP;
        float v = sf[0] + Mc[j];
#pragma unroll
        for (int k = 1; k < 9; ++k) v = fmaxf(v, sf[k] + Mc[k * EP + j]);
        s = v;
    }
    s += endT[j];
    float sf[9];
#pragma unroll
    for (int k = 0; k < 9; ++k) sf[k] = __shfl(s, k, 64);
    if (lane == 0) {
        float best = sf[0]; int bi = 0;
#pragma unroll
        for (int k = 1; k < 9; ++k) if (sf[k] > best) { best = sf[k]; bi = k; }
        score_out[b] = best;
        ltag[b] = bi;
    }
}

// K4: per-chunk forward replay from boundary vector: writes hist (argmax per
// step) and the chunk's backtrace composition map. lane = c_sub*9 + j.
__global__ __launch_bounds__(64) void k_replay(const float* __restrict__ emis,
                                               const float* __restrict__ trans,
                                               const int* __restrict__ lenw,
                                               const float* __restrict__ sb,
                                               uint8_t* __restrict__ hist,
                                               uint8_t* __restrict__ comp) {
    const int b = blockIdx.x / WPB;
    const int w = blockIdx.x % WPB;
    const int lane = threadIdx.x;
    const int cs = lane / 9, j = lane % 9;
    const int c = w * GPW + cs;
    const bool act = (lane < 63) && (c < Cn);
    const int cc = act ? c : 0;
    const int base = cs * 9;
    const int len = lenw[b];

    float tcol[9];
#pragma unroll
    for (int i = 0; i < 9; ++i) tcol[i] = trans[i * 9 + j];

    float s = sb[(size_t)(b * Cn + cc) * EP + j];
    int cmp = j;
    const float* erow = emis + (size_t)b * Ln * EP;
    uint8_t* hb = hist + (size_t)b * Ln * HP;
    const int l0 = 1 + cc * Sn;

    for (int t = 0; t < Sn; ++t) {
        const int l = l0 + t;
        const int le = (l < Ln) ? l : (Ln - 1);
        float sf[9];
#pragma unroll
        for (int i = 0; i < 9; ++i) sf[i] = __shfl(s, base + i, 64);
        float best = sf[0] + tcol[0]; int idx = 0;
#pragma unroll
        for (int i = 1; i < 9; ++i) {
            const float v = sf[i] + tcol[i];
            if (v > best) { best = v; idx = i; }   // strict >: first-max
        }
        const bool msk = act && (l < len);
        const float em = erow[le * EP + j];
        s = msk ? best + em : s;
        idx = msk ? idx : j;                        // masked step = identity
        if (act && l < Ln) hb[l * HP + j] = (uint8_t)idx;
        cmp = __shfl(cmp, base + idx, 64);          // comp[j] <- comp[idx]
    }
    if (act) comp[(size_t)(b * Cn + c) * HP + j] = (uint8_t)cmp;
}

// K5: sequential walk over 32 comp maps -> chunk-end tags; writes tags[b][0].
__global__ __launch_bounds__(64) void k_stitch_tags(const uint8_t* __restrict__ comp,
                                                    const int* __restrict__ ltag,
                                                    uint8_t* __restrict__ bt,
                                                    float* __restrict__ tags) {
    const int b = blockIdx.x * 64 + threadIdx.x;
    if (b >= Bn) return;
    int t = ltag[b];
    for (int c = Cn - 1; c >= 0; --c) {
        bt[b * Cn + c] = (uint8_t)t;                // tag at l = hi(c)-1
        t = comp[(size_t)(b * Cn + c) * HP + t];    // tag at l = lo(c)-1
    }
    tags[(size_t)b * Ln] = (float)t;                // l=0 (mask[:,0] always true)
}

// K6: lane-per-chunk backward hist walk, writes tags[b][1..1023].
__global__ __launch_bounds__(64) void k_writetags(const uint8_t* __restrict__ hist,
                                                  const uint8_t* __restrict__ bt,
                                                  const int* __restrict__ lenw,
                                                  float* __restrict__ tags) {
    const int g = blockIdx.x * 64 + threadIdx.x;    // 0..4095
    const int b = g >> 5, c = g & 31;
    const int len = lenw[b];
    const uint8_t* hb = hist + (size_t)b * Ln * HP;
    int t = bt[b * Cn + c];
    const int lo = 1 + c * Sn;
    const int hi = (lo + Sn < Ln) ? lo + Sn : Ln;
    for (int l = hi - 1; l >= lo; --l) {
        tags[(size_t)b * Ln + l] = (l < len) ? (float)t : 0.f;
        t = hb[l * HP + t];
    }
}

// ---------------------------------------------------------------------------
extern "C" void kernel_launch(void* const* d_in, const int* in_sizes, int n_in,
                              void* d_out, int out_size, void* d_ws, size_t ws_size,
                              hipStream_t stream) {
    const float* enc    = (const float*)d_in[0];
    const void*  mask   = d_in[1];
    const float* W      = (const float*)d_in[2];
    const float* bias   = (const float*)d_in[3];
    const float* startT = (const float*)d_in[4];
    const float* endT   = (const float*)d_in[5];
    const float* trans  = (const float*)d_in[6];

    float* out_tags  = (float*)d_out;
    float* out_score = out_tags + (size_t)Bn * Ln;

    char* ws = (char*)d_ws;
    float*   emis = (float*)(ws);
    float*   Mws  = (float*)(ws + 6291456);
    float*   sb   = (float*)(ws + 8060928);
    uint8_t* hist = (uint8_t*)(ws + 8257536);
    uint8_t* comp = (uint8_t*)(ws + 10354688);
    int*     lenw = (int*)(ws + 10420224);
    int*     ltag = (int*)(ws + 10420736);
    uint8_t* bt   = (uint8_t*)(ws + 10421248);

    k_len<<<Bn, 64, 0, stream>>>(mask, lenw);
    k_emis<<<1024, 256, 0, stream>>>(enc, W, bias, emis);
    k_chunkmat<<<Bn * WPB, 64, 0, stream>>>(emis, trans, lenw, Mws);
    k_stitch_scores<<<Bn, 64, 0, stream>>>(emis, Mws, startT, endT, sb, out_score, ltag);
    k_replay<<<Bn * WPB, 64, 0, stream>>>(emis, trans, lenw, sb, hist, comp);
    k_stitch_tags<<<(Bn + 63) / 64, 64, 0, stream>>>(comp, ltag, bt, out_tags);
    k_writetags<<<64, 64, 0, stream>>>(hist, bt, lenw, out_tags);
}

// Round 3
// 732.613 us; speedup vs baseline: 1.4976x; 1.0513x over previous
//
#include <hip/hip_runtime.h>
#include <stdint.h>

#define Bn 128
#define Ln 1024
#define H2n 1024
#define Tn 9
#define Cn 32          // chunks per batch (steps l=1..1023 in 32-step chunks)
#define Sn 32          // steps per chunk (last chunk has 31)
#define GPW 7          // chunk-groups per wave (7*9 = 63 active lanes)
#define EP 12          // padded emissions row stride (floats)
#define HP 16          // hist/comp row stride (bytes)
#define NEG (-1e30f)

// ws layout: emis_p f32 [B][L][EP] @ 0  (6,291,456 B). Everything else is LDS.

// mask storage detection (lengths>=512 so mask[0][1..4] all true):
__device__ __forceinline__ int mask_mode(const void* m) {
    const uint8_t* p = (const uint8_t*)m;
    return (p[1] == 1) ? 0 : ((p[4] == 1) ? 1 : 2);
}
__device__ __forceinline__ bool mask_get(const void* m, int mode, int idx) {
    if (mode == 0) return ((const uint8_t*)m)[idx] != 0;
    if (mode == 1) return ((const int*)m)[idx] != 0;
    return ((const long long*)m)[idx] != 0;
}

// ---------------------------------------------------------------------------
// K1: emissions, padded to EP floats/row. wave-per-row, W in LDS. (unchanged)
// ---------------------------------------------------------------------------
__global__ __launch_bounds__(256) void k_emis(const float* __restrict__ enc,
                                              const float* __restrict__ W,
                                              const float* __restrict__ bias,
                                              float* __restrict__ emis) {
    __shared__ float Wl[Tn * H2n];
    __shared__ float bl[Tn];
    const int tid = threadIdx.x;
    for (int i = tid; i < Tn * H2n; i += 256) Wl[i] = W[i];
    if (tid < Tn) bl[tid] = bias[tid];
    __syncthreads();

    const int lane = tid & 63;
    const int wave = tid >> 6;
    const int wid  = blockIdx.x * 4 + wave;
    const int row0 = wid * 32;

    for (int rr = 0; rr < 32; ++rr) {
        const int row = row0 + rr;
        const float4* rp = (const float4*)(enc + (size_t)row * H2n);
        float acc[Tn];
#pragma unroll
        for (int t = 0; t < Tn; ++t) acc[t] = 0.f;
#pragma unroll
        for (int j = 0; j < 4; ++j) {
            const float4 ev = rp[lane + j * 64];
#pragma unroll
            for (int t = 0; t < Tn; ++t) {
                const float4 wv = ((const float4*)(Wl + t * H2n))[lane + j * 64];
                acc[t] += ev.x * wv.x + ev.y * wv.y + ev.z * wv.z + ev.w * wv.w;
            }
        }
#pragma unroll
        for (int t = 0; t < Tn; ++t) {
#pragma unroll
            for (int off = 32; off > 0; off >>= 1)
                acc[t] += __shfl_xor(acc[t], off, 64);
        }
        if (lane == 0) {
            float* op = emis + (size_t)row * EP;
            *((float4*)op)       = make_float4(acc[0] + bl[0], acc[1] + bl[1],
                                               acc[2] + bl[2], acc[3] + bl[3]);
            *((float4*)(op + 4)) = make_float4(acc[4] + bl[4], acc[5] + bl[5],
                                               acc[6] + bl[6], acc[7] + bl[7]);
            *((float4*)(op + 8)) = make_float4(acc[8] + bl[8], 0.f, 0.f, 0.f);
        }
    }
}

// ---------------------------------------------------------------------------
// K2: entire Viterbi (fwd scan + backtrace) for one batch per block.
// 320 threads = 5 waves. All intermediate state in LDS (~33 KB).
// Phases (identical math to round-2 kernels, storage global->LDS):
//   0 len | 1 chunkmat | 2 stitch_scores (wave0) | 3 replay |
//   4 stitch_tags (thr0) | 5a tag-walk (32 lanes) | 5b coalesced store
// ---------------------------------------------------------------------------
__global__ __launch_bounds__(320) void k_viterbi_all(const float* __restrict__ emis,
                                                     const void* __restrict__ maskraw,
                                                     const float* __restrict__ startT,
                                                     const float* __restrict__ endT,
                                                     const float* __restrict__ trans,
                                                     float* __restrict__ tags,
                                                     float* __restrict__ score_out) {
    __shared__ float   Ml[Cn * 9 * EP];   // chunk matrices    13,824 B
    __shared__ float   sbl[Cn * EP];      // boundary vectors   1,536 B
    __shared__ uint8_t hl[Ln * HP];       // argmax history    16,384 B
    __shared__ uint8_t cl[Cn * HP];       // comp maps            512 B
    __shared__ uint8_t btl[Cn];           // chunk-end tags
    __shared__ uint8_t tagrow[Ln];        // final tags (u8)    1,024 B
    __shared__ int lenl, ltagl;

    const int b    = blockIdx.x;
    const int tid  = threadIdx.x;
    const int wave = tid >> 6;
    const int lane = tid & 63;

    // ---- phase 0: per-batch length (mask row is a prefix of trues) ----
    if (wave == 0) {
        const int mode = mask_mode(maskraw);
        int cnt = 0;
        for (int k = 0; k < Ln / 64; ++k)
            cnt += mask_get(maskraw, mode, b * Ln + lane + k * 64) ? 1 : 0;
#pragma unroll
        for (int off = 32; off > 0; off >>= 1) cnt += __shfl_xor(cnt, off, 64);
        if (lane == 0) lenl = cnt;
    }
    __syncthreads();
    const int len = lenl;

    const float* erow = emis + (size_t)b * Ln * EP;
    const int cs = lane / 9;
    const int ii = lane % 9;                 // matrix row (ph1) / tag col (ph3)
    const int c  = wave * GPW + cs;
    const bool act = (lane < 63) && (c < Cn);
    const int cc = act ? c : 0;
    const int l0 = 1 + cc * Sn;

    // ---- phase 1: per-chunk max-plus matrix product ----
    {
        float tr[81];
#pragma unroll
        for (int k = 0; k < 81; ++k) tr[k] = trans[k];
        float m[9];
#pragma unroll
        for (int k = 0; k < 9; ++k) m[k] = (k == ii) ? 0.f : NEG;
#pragma unroll
        for (int t = 0; t < Sn; ++t) {
            const int l = l0 + t;
            const int le = (l < Ln) ? l : (Ln - 1);
            const float4 ea  = *((const float4*)(erow + le * EP));
            const float4 eb4 = *((const float4*)(erow + le * EP + 4));
            const float  e8v = erow[le * EP + 8];
            const float e[9] = {ea.x, ea.y, ea.z, ea.w, eb4.x, eb4.y, eb4.z, eb4.w, e8v};
            const bool ds = act && (l < len);
            float nm[9];
#pragma unroll
            for (int j = 0; j < 9; ++j) {
                float v = m[0] + tr[j];
#pragma unroll
                for (int k = 1; k < 9; ++k) v = fmaxf(v, m[k] + tr[k * 9 + j]);
                nm[j] = v + e[j];
            }
#pragma unroll
            for (int j = 0; j < 9; ++j) m[j] = ds ? nm[j] : m[j];
        }
        if (act) {
            float* Mr = Ml + (size_t)(c * 9 + ii) * EP;
            *((float4*)Mr)       = make_float4(m[0], m[1], m[2], m[3]);
            *((float4*)(Mr + 4)) = make_float4(m[4], m[5], m[6], m[7]);
            *((float4*)(Mr + 8)) = make_float4(m[8], 0.f, 0.f, 0.f);
        }
    }
    __syncthreads();

    // ---- phase 2: sequential stitch over chunk matrices (wave 0) ----
    if (wave == 0) {
        const int j = (lane < Tn) ? lane : 0;
        float s = startT[j] + erow[j];
        for (int c2 = 0; c2 < Cn; ++c2) {
            if (lane < Tn) sbl[c2 * EP + j] = s;
            float sf[9];
#pragma unroll
            for (int k = 0; k < 9; ++k) sf[k] = __shfl(s, k, 64);
            const float* Mc = Ml + (size_t)c2 * 9 * EP;
            float v = sf[0] + Mc[j];
#pragma unroll
            for (int k = 1; k < 9; ++k) v = fmaxf(v, sf[k] + Mc[k * EP + j]);
            s = v;
        }
        s += endT[j];
        float sf[9];
#pragma unroll
        for (int k = 0; k < 9; ++k) sf[k] = __shfl(s, k, 64);
        if (lane == 0) {
            float best = sf[0]; int bi = 0;
#pragma unroll
            for (int k = 1; k < 9; ++k) if (sf[k] > best) { best = sf[k]; bi = k; }
            score_out[b] = best;
            ltagl = bi;
        }
    }
    __syncthreads();

    // ---- phase 3: per-chunk replay -> hist + comp maps ----
    {
        const int j = ii;
        const int base = cs * 9;
        float tcol[9];
#pragma unroll
        for (int i = 0; i < 9; ++i) tcol[i] = trans[i * 9 + j];
        float s = sbl[cc * EP + j];
        int cmp = j;
        for (int t = 0; t < Sn; ++t) {
            const int l = l0 + t;
            const int le = (l < Ln) ? l : (Ln - 1);
            float sf[9];
#pragma unroll
            for (int i = 0; i < 9; ++i) sf[i] = __shfl(s, base + i, 64);
            float best = sf[0] + tcol[0]; int idx = 0;
#pragma unroll
            for (int i = 1; i < 9; ++i) {
                const float v = sf[i] + tcol[i];
                if (v > best) { best = v; idx = i; }   // strict >: first-max
            }
            const bool msk = act && (l < len);
            const float em = erow[le * EP + j];
            s = msk ? best + em : s;
            idx = msk ? idx : j;                        // masked step = identity
            if (act && l < Ln) hl[l * HP + j] = (uint8_t)idx;
            cmp = __shfl(cmp, base + idx, 64);          // comp[j] <- comp[idx]
        }
        if (act) cl[c * HP + j] = (uint8_t)cmp;
    }
    __syncthreads();

    // ---- phase 4: walk comp maps -> chunk-end tags (thread 0) ----
    if (tid == 0) {
        int t = ltagl;
        for (int c2 = Cn - 1; c2 >= 0; --c2) {
            btl[c2] = (uint8_t)t;
            t = cl[c2 * HP + t];
        }
        tagrow[0] = (uint8_t)t;   // l=0: mask[:,0] always true
    }
    __syncthreads();

    // ---- phase 5a: per-chunk backward hist walk into tagrow ----
    if (tid < Cn) {
        int t = btl[tid];
        const int lo = 1 + tid * Sn;
        const int hi = (lo + Sn < Ln) ? lo + Sn : Ln;
        for (int l = hi - 1; l >= lo; --l) {
            tagrow[l] = (l < len) ? (uint8_t)t : 0;
            t = hl[l * HP + t];
        }
    }
    __syncthreads();

    // ---- phase 5b: coalesced tag store ----
    for (int l = tid; l < Ln; l += 320)
        tags[(size_t)b * Ln + l] = (float)tagrow[l];
}

// ---------------------------------------------------------------------------
extern "C" void kernel_launch(void* const* d_in, const int* in_sizes, int n_in,
                              void* d_out, int out_size, void* d_ws, size_t ws_size,
                              hipStream_t stream) {
    const float* enc    = (const float*)d_in[0];
    const void*  mask   = d_in[1];
    const float* W      = (const float*)d_in[2];
    const float* bias   = (const float*)d_in[3];
    const float* startT = (const float*)d_in[4];
    const float* endT   = (const float*)d_in[5];
    const float* trans  = (const float*)d_in[6];

    float* out_tags  = (float*)d_out;
    float* out_score = out_tags + (size_t)Bn * Ln;

    float* emis = (float*)d_ws;

    k_emis<<<1024, 256, 0, stream>>>(enc, W, bias, emis);
    k_viterbi_all<<<Bn, 320, 0, stream>>>(emis, mask, startT, endT, trans,
                                          out_tags, out_score);
}